// Round 2
// baseline (170.919 us; speedup 1.0000x reference)
//
#include <hip/hip_runtime.h>
#include <hip/hip_bf16.h>

#define NB 8
#define NN 256
#define DIMV 256
#define DI 64
#define NEGMAX 3.402823466e+38f

typedef unsigned short u16;
typedef unsigned int u32;
typedef __attribute__((ext_vector_type(8))) short bf16x8;
typedef __attribute__((ext_vector_type(4))) float f32x4;
typedef __attribute__((ext_vector_type(2))) float f32x2;
typedef __attribute__((ext_vector_type(2))) unsigned int u32x2;

__device__ __forceinline__ u16 f2bf(float f) {
    __hip_bfloat16 h = __float2bfloat16(f);
    u16 u; __builtin_memcpy(&u, &h, 2); return u;
}
__device__ __forceinline__ u32 pack2(float a, float b) {
    return (u32)f2bf(a) | ((u32)f2bf(b) << 16);
}
__device__ __forceinline__ float ubf_lo(u32 u) {
    union { u32 u; float f; } x; x.u = u << 16; return x.f;
}
__device__ __forceinline__ float ubf_hi(u32 u) {
    union { u32 u; float f; } x; x.u = u & 0xffff0000u; return x.f;
}
// swizzles: fA for 128B-stride rows, fB for 64B-stride rows (bits 4-6 only)
__device__ __forceinline__ int fA(int row) { return ((row & 7) << 4) ^ ((row & 8) << 2); }
__device__ __forceinline__ int fB(int row) { return ((row >> 1) & 7) << 4; }

// ---------------------------------------------------------------------------
// prep 1: transpose + bf16-convert GEMM B-operand weights
// ---------------------------------------------------------------------------
__global__ void prep_w(const float* __restrict__ w1, const float* __restrict__ w2,
                       const float* __restrict__ pw2,
                       u16* __restrict__ w1t, u16* __restrict__ w2t, u16* __restrict__ pw2t)
{
    int idx = blockIdx.x * 256 + threadIdx.x;
    if (idx < 16384) {
        { int o = idx >> 6, kk = idx & 63;  w1t[idx] = f2bf(w1[kk * 256 + o]); }
        { int d = idx >> 8, h  = idx & 255; w2t[idx] = f2bf(w2[h * 64 + d]); }
    }
    if (idx < 4096) { int d = idx >> 6, h = idx & 63; pw2t[idx] = f2bf(pw2[h * 64 + d]); }
}

// ---------------------------------------------------------------------------
// prep 2: q = x@theta_w, k = y@phi_w, v = y@g_w   (all (B,N,64) f32 into ws)
// ---------------------------------------------------------------------------
__global__ void prep_qkv(const float* __restrict__ x, const float* __restrict__ y,
                         const float* __restrict__ tw, const float* __restrict__ pw,
                         const float* __restrict__ gw,
                         float* __restrict__ q, float* __restrict__ k, float* __restrict__ v)
{
    __shared__ float xs[4][256];
    __shared__ float ys[4][256];
    const int blk = blockIdx.x;
    const int b = blk >> 6;
    const int n0 = (blk & 63) * 4;
    const int tid = threadIdx.x;
    {
        int r = tid >> 6, e = tid & 63;
        ((float4*)xs[r])[e] = ((const float4*)(x + (size_t)(b * NN + n0 + r) * DIMV))[e];
        ((float4*)ys[r])[e] = ((const float4*)(y + (size_t)(b * NN + n0 + r) * DIMV))[e];
    }
    __syncthreads();
    const int nl = tid >> 6, d = tid & 63;
    float aq = 0.f, ak = 0.f, av = 0.f;
    #pragma unroll 4
    for (int c = 0; c < 256; ++c) {
        float wq = tw[c * 64 + d], wk = pw[c * 64 + d], wv = gw[c * 64 + d];
        float xv = xs[nl][c], yv = ys[nl][c];
        aq += xv * wq; ak += yv * wk; av += yv * wv;
    }
    const int n = n0 + nl;
    q[(b * NN + n) * DI + d] = aq;
    k[(b * NN + n) * DI + d] = ak;
    v[(b * NN + n) * DI + d] = av;
}

// ---------------------------------------------------------------------------
// main fused kernel: one block per (b, i); 4 waves; wave owns rows j0..j0+63.
// Column-interleaved B-fragments: accR/accS col = 4*l15+ct, Hc col = 2*l15+c2.
// ---------------------------------------------------------------------------
__global__ __launch_bounds__(256, 3)
void fused_attn(const float* __restrict__ x, const float* __restrict__ x_pos,
                const float* __restrict__ y_pos, const int* __restrict__ mask,
                const float* __restrict__ pw1, const float* __restrict__ pb1,
                const float* __restrict__ pb2,
                const float* __restrict__ ab1, const float* __restrict__ ab2,
                const float* __restrict__ out_w,
                const float* __restrict__ qg, const float* __restrict__ kg,
                const float* __restrict__ vg,
                const u16* __restrict__ w1t, const u16* __restrict__ w2t,
                const u16* __restrict__ pw2t,
                float* __restrict__ out)
{
    __shared__ u16 sT[NN * DI];     // 32 KB: T (swizzled fA)
    __shared__ u16 sH[NN * 32];     // 16 KB: Hc chunk (swizzled fB)
    __shared__ float sRed[832];     // 3.3 KB: redm/reds/reda/sAgg

    const int blk = blockIdx.x;
    const int b = blk >> 8;
    const int i = blk & 255;
    const int tid = threadIdx.x;
    const int l   = tid & 63;
    const int w   = tid >> 6;
    const int j0  = w * 64;
    const int l15 = l & 15;
    const int lh  = l >> 4;

    char* sTB = (char*)sT;
    char* sHB = (char*)sH;
    float* redm = sRed;
    float* reds = sRed + 256;
    float* reda = sRed + 512;
    float* sAgg = sRed + 768;

    // ---- phase 0: pos-MLP layer 1 directly into GEMM0 A-fragments ----
    const float xp0 = x_pos[(b * NN + i) * 3 + 0];
    const float xp1 = x_pos[(b * NN + i) * 3 + 1];
    const float xp2 = x_pos[(b * NN + i) * 3 + 2];

    float w1r[2][4][8];     // [ks][{w0,w1,w2,b1}][cc] for my cols ks*32+lh*8+cc
    #pragma unroll
    for (int ks = 0; ks < 2; ++ks) {
        const int c0 = ks * 32 + lh * 8;
        #pragma unroll
        for (int qq = 0; qq < 2; ++qq) {
            *(f32x4*)&w1r[ks][0][qq*4] = *(const f32x4*)&pw1[0*64 + c0 + qq*4];
            *(f32x4*)&w1r[ks][1][qq*4] = *(const f32x4*)&pw1[1*64 + c0 + qq*4];
            *(f32x4*)&w1r[ks][2][qq*4] = *(const f32x4*)&pw1[2*64 + c0 + qq*4];
            *(f32x4*)&w1r[ks][3][qq*4] = *(const f32x4*)&pb1[c0 + qq*4];
        }
    }
    bf16x8 af[4][2];
    #pragma unroll
    for (int rt = 0; rt < 4; ++rt) {
        const int row = j0 + rt * 16 + l15;
        const float* yp = y_pos + (size_t)(b * NN + row) * 3;
        const float r0 = xp0 - yp[0], r1 = xp1 - yp[1], r2 = xp2 - yp[2];
        #pragma unroll
        for (int ks = 0; ks < 2; ++ks) {
            bf16x8 v;
            #pragma unroll
            for (int cc = 0; cc < 8; ++cc) {
                float h = w1r[ks][3][cc] + r0 * w1r[ks][0][cc] + r1 * w1r[ks][1][cc] + r2 * w1r[ks][2][cc];
                v[cc] = (short)f2bf(fmaxf(h, 0.f));
            }
            af[rt][ks] = v;
        }
    }

    // ---- GEMM0: RPE = hidden @ pos_w2, col-interleaved (col = 4*l15+ct) ----
    f32x4 accR[4][4];
    {
        bf16x8 bfr[4][2];
        #pragma unroll
        for (int ct = 0; ct < 4; ++ct)
            #pragma unroll
            for (int ks = 0; ks < 2; ++ks) {
                const int d = 4 * l15 + ct;
                bfr[ct][ks] = *(const bf16x8*)(pw2t + d * 64 + ks * 32 + lh * 8);
            }
        #pragma unroll
        for (int rt = 0; rt < 4; ++rt)
            #pragma unroll
            for (int ct = 0; ct < 4; ++ct) {
                f32x4 a = {0.f, 0.f, 0.f, 0.f};
                a = __builtin_amdgcn_mfma_f32_16x16x32_bf16(af[rt][0], bfr[ct][0], a, 0, 0, 0);
                a = __builtin_amdgcn_mfma_f32_16x16x32_bf16(af[rt][1], bfr[ct][1], a, 0, 0, 0);
                accR[rt][ct] = a;
            }
    }

    // ---- epilogue: T -> sT (b64, swizzled); v_full packed bf16 in regs ----
    const f32x4 qv   = *(const f32x4*)&qg[((size_t)b * NN + i) * DI + 4 * l15];
    const f32x4 pb2v = *(const f32x4*)&pb2[4 * l15];
    u32 accVp[4][4][2];
    #pragma unroll
    for (int rt = 0; rt < 4; ++rt)
        #pragma unroll
        for (int r = 0; r < 4; ++r) {
            const int row = j0 + rt * 16 + lh * 4 + r;
            const f32x4 kv = *(const f32x4*)&kg[((size_t)b * NN + row) * DI + 4 * l15];
            const f32x4 vv = *(const f32x4*)&vg[((size_t)b * NN + row) * DI + 4 * l15];
            float tv[4], vf[4];
            #pragma unroll
            for (int ct = 0; ct < 4; ++ct) {
                const float rpe = accR[rt][ct][r] + pb2v[ct];
                tv[ct] = qv[ct] - kv[ct] + rpe;
                vf[ct] = vv[ct] + rpe;
            }
            u32x2 tpk; tpk[0] = pack2(tv[0], tv[1]); tpk[1] = pack2(tv[2], tv[3]);
            *(u32x2*)(sTB + ((row * 128 + l15 * 8) ^ fA(row))) = tpk;
            accVp[rt][r][0] = pack2(vf[0], vf[1]);
            accVp[rt][r][1] = pack2(vf[2], vf[3]);
        }

    // ---- chunk loop: 8 chunks of 32 hidden; SIM accumulates in regs ----
    f32x4 accS[4][4];
    #pragma unroll
    for (int rt = 0; rt < 4; ++rt)
        #pragma unroll
        for (int ct = 0; ct < 4; ++ct) accS[rt][ct] = (f32x4){0.f, 0.f, 0.f, 0.f};

    for (int hc = 0; hc < 8; ++hc) {
        // pass 1: GEMM1 (Hc col = 2*l15+c2) + relu + packed b32 store
        bf16x8 b1f[2][2];
        #pragma unroll
        for (int c2 = 0; c2 < 2; ++c2)
            #pragma unroll
            for (int ks = 0; ks < 2; ++ks) {
                const int hid = hc * 32 + 2 * l15 + c2;
                b1f[c2][ks] = *(const bf16x8*)(w1t + hid * 64 + ks * 32 + lh * 8);
            }
        const f32x2 ab1v = *(const f32x2*)&ab1[hc * 32 + 2 * l15];
        #pragma unroll
        for (int rt = 0; rt < 4; ++rt) {
            const int rowA = j0 + rt * 16 + l15;
            const int swA = fA(rowA);
            bf16x8 aT0 = *(const bf16x8*)(sTB + ((rowA * 128 + lh * 16) ^ swA));
            bf16x8 aT1 = *(const bf16x8*)(sTB + ((rowA * 128 + 64 + lh * 16) ^ swA));
            f32x4 h0 = {0.f,0.f,0.f,0.f}, h1 = {0.f,0.f,0.f,0.f};
            h0 = __builtin_amdgcn_mfma_f32_16x16x32_bf16(aT0, b1f[0][0], h0, 0, 0, 0);
            h0 = __builtin_amdgcn_mfma_f32_16x16x32_bf16(aT1, b1f[0][1], h0, 0, 0, 0);
            h1 = __builtin_amdgcn_mfma_f32_16x16x32_bf16(aT0, b1f[1][0], h1, 0, 0, 0);
            h1 = __builtin_amdgcn_mfma_f32_16x16x32_bf16(aT1, b1f[1][1], h1, 0, 0, 0);
            #pragma unroll
            for (int r = 0; r < 4; ++r) {
                const int row = j0 + rt * 16 + lh * 4 + r;
                u32 pk = pack2(fmaxf(h0[r] + ab1v[0], 0.f), fmaxf(h1[r] + ab1v[1], 0.f));
                *(u32*)(sHB + ((row * 64 + l15 * 4) ^ fB(row))) = pk;
            }
        }
        // pass 2: GEMM2 (SIM col = 4*l15+ct), k = 32 (one MFMA per tile)
        bf16x8 b2f[4];
        #pragma unroll
        for (int ct = 0; ct < 4; ++ct) {
            const int d = 4 * l15 + ct;
            b2f[ct] = *(const bf16x8*)(w2t + d * 256 + hc * 32 + lh * 8);
        }
        #pragma unroll
        for (int rt = 0; rt < 4; ++rt) {
            const int rowA = j0 + rt * 16 + l15;
            bf16x8 a2 = *(const bf16x8*)(sHB + ((rowA * 64 + lh * 16) ^ fB(rowA)));
            #pragma unroll
            for (int ct = 0; ct < 4; ++ct)
                accS[rt][ct] = __builtin_amdgcn_mfma_f32_16x16x32_bf16(a2, b2f[ct], accS[rt][ct], 0, 0, 0);
        }
    }

    // ---- softmax: fully in-register over accS; cross-lane + cross-wave ----
    const f32x4 ab2v = *(const f32x4*)&ab2[4 * l15];
    const int mjl = mask[b * NN + j0 + l];
    const unsigned long long mb = __ballot(mjl != 0);
    const bool mi_b = mask[b * NN + i] != 0;

    float mx[4] = {-NEGMAX, -NEGMAX, -NEGMAX, -NEGMAX};
    #pragma unroll
    for (int rt = 0; rt < 4; ++rt)
        #pragma unroll
        for (int r = 0; r < 4; ++r) {
            const int ro = rt * 16 + lh * 4 + r;
            const bool bit = mi_b && ((mb >> ro) & 1ull);
            #pragma unroll
            for (int ct = 0; ct < 4; ++ct) {
                float s = bit ? (accS[rt][ct][r] + ab2v[ct]) : -NEGMAX;
                accS[rt][ct][r] = s;
                mx[ct] = fmaxf(mx[ct], s);
            }
        }
    #pragma unroll
    for (int ct = 0; ct < 4; ++ct) {
        mx[ct] = fmaxf(mx[ct], __shfl_xor(mx[ct], 16));
        mx[ct] = fmaxf(mx[ct], __shfl_xor(mx[ct], 32));
    }
    if (lh == 0)
        *(f32x4*)&redm[w * 64 + 4 * l15] = (f32x4){mx[0], mx[1], mx[2], mx[3]};
    __syncthreads();
    float m4[4];
    {
        f32x4 a0 = *(f32x4*)&redm[      4 * l15];
        f32x4 a1 = *(f32x4*)&redm[ 64 + 4 * l15];
        f32x4 a2 = *(f32x4*)&redm[128 + 4 * l15];
        f32x4 a3 = *(f32x4*)&redm[192 + 4 * l15];
        #pragma unroll
        for (int ct = 0; ct < 4; ++ct)
            m4[ct] = fmaxf(fmaxf(a0[ct], a1[ct]), fmaxf(a2[ct], a3[ct]));
    }
    float ssum[4] = {0.f, 0.f, 0.f, 0.f}, sagg[4] = {0.f, 0.f, 0.f, 0.f};
    #pragma unroll
    for (int rt = 0; rt < 4; ++rt)
        #pragma unroll
        for (int r = 0; r < 4; ++r) {
            const u32 p0 = accVp[rt][r][0], p1 = accVp[rt][r][1];
            const float vfs[4] = {ubf_lo(p0), ubf_hi(p0), ubf_lo(p1), ubf_hi(p1)};
            #pragma unroll
            for (int ct = 0; ct < 4; ++ct) {
                const float e = __expf(accS[rt][ct][r] - m4[ct]);
                ssum[ct] += e;
                sagg[ct] += e * vfs[ct];
            }
        }
    #pragma unroll
    for (int ct = 0; ct < 4; ++ct) {
        ssum[ct] += __shfl_xor(ssum[ct], 16);
        ssum[ct] += __shfl_xor(ssum[ct], 32);
        sagg[ct] += __shfl_xor(sagg[ct], 16);
        sagg[ct] += __shfl_xor(sagg[ct], 32);
    }
    if (lh == 0) {
        *(f32x4*)&reds[w * 64 + 4 * l15] = (f32x4){ssum[0], ssum[1], ssum[2], ssum[3]};
        *(f32x4*)&reda[w * 64 + 4 * l15] = (f32x4){sagg[0], sagg[1], sagg[2], sagg[3]};
    }
    __syncthreads();
    if (tid < 64) {
        float den = reds[tid] + reds[64 + tid] + reds[128 + tid] + reds[192 + tid];
        float ag  = reda[tid] + reda[64 + tid] + reda[128 + tid] + reda[192 + tid];
        sAgg[tid] = ag / den;
    }
    __syncthreads();

    // ---- phase 4: out[i,:] = x[i,:] + agg @ out_w ----
    {
        float acc = 0.f;
        #pragma unroll 8
        for (int d = 0; d < 64; ++d)
            acc += sAgg[d] * out_w[d * DIMV + tid];
        const int o = (b * NN + i) * DIMV + tid;
        out[o] = x[o] + acc;
    }
}

// ---------------------------------------------------------------------------
extern "C" void kernel_launch(void* const* d_in, const int* in_sizes, int n_in,
                              void* d_out, int out_size, void* d_ws, size_t ws_size,
                              hipStream_t stream)
{
    const float* x       = (const float*)d_in[0];
    const float* y       = (const float*)d_in[1];
    const float* x_pos   = (const float*)d_in[2];
    const float* y_pos   = (const float*)d_in[3];
    const int*   mask    = (const int*)d_in[4];
    const float* g_w     = (const float*)d_in[5];
    const float* theta_w = (const float*)d_in[6];
    const float* phi_w   = (const float*)d_in[7];
    const float* pos_w1  = (const float*)d_in[8];
    const float* pos_b1  = (const float*)d_in[9];
    const float* pos_w2  = (const float*)d_in[10];
    const float* pos_b2  = (const float*)d_in[11];
    const float* attn_w1 = (const float*)d_in[12];
    const float* attn_b1 = (const float*)d_in[13];
    const float* attn_w2 = (const float*)d_in[14];
    const float* attn_b2 = (const float*)d_in[15];
    const float* out_w   = (const float*)d_in[16];

    float* q = (float*)d_ws;
    float* k = q + NB * NN * DI;
    float* v = k + NB * NN * DI;
    u16* w1t  = (u16*)(v + NB * NN * DI);   // 256*64
    u16* w2t  = w1t + 256 * 64;             // 64*256
    u16* pw2t = w2t + 64 * 256;             // 64*64

    prep_w<<<64, 256, 0, stream>>>(attn_w1, attn_w2, pos_w2, w1t, w2t, pw2t);
    prep_qkv<<<512, 256, 0, stream>>>(x, y, theta_w, phi_w, g_w, q, k, v);
    fused_attn<<<NB * NN, 256, 0, stream>>>(x, x_pos, y_pos, mask,
                                            pos_w1, pos_b1, pos_b2,
                                            attn_b1, attn_b2, out_w,
                                            q, k, v, w1t, w2t, pw2t,
                                            (float*)d_out);
}

// Round 3
// 118.887 us; speedup vs baseline: 1.4377x; 1.4377x over previous
//
#include <hip/hip_runtime.h>
#include <hip/hip_bf16.h>

#define NB 8
#define NN 256
#define DIMV 256
#define DI 64
#define NEGMAX 3.402823466e+38f

typedef unsigned short u16;
typedef unsigned int u32;
typedef __attribute__((ext_vector_type(8))) short bf16x8;
typedef __attribute__((ext_vector_type(4))) float f32x4;
typedef __attribute__((ext_vector_type(2))) float f32x2;
typedef __attribute__((ext_vector_type(2))) unsigned int u32x2;

__device__ __forceinline__ u16 f2bf(float f) {
    __hip_bfloat16 h = __float2bfloat16(f);
    u16 u; __builtin_memcpy(&u, &h, 2); return u;
}
__device__ __forceinline__ u32 pack2(float a, float b) {
    return (u32)f2bf(a) | ((u32)f2bf(b) << 16);
}
__device__ __forceinline__ float ubf_lo(u32 u) {
    union { u32 u; float f; } x; x.u = u << 16; return x.f;
}
__device__ __forceinline__ float ubf_hi(u32 u) {
    union { u32 u; float f; } x; x.u = u & 0xffff0000u; return x.f;
}
// swizzles: fA for 128B-stride rows, fB for 64B-stride rows (bits 4-6 only)
__device__ __forceinline__ int fA(int row) { return ((row & 7) << 4) ^ ((row & 8) << 2); }
__device__ __forceinline__ int fB(int row) { return ((row >> 1) & 7) << 4; }

// ---------------------------------------------------------------------------
// prep 1: transpose + bf16-convert GEMM B-operand weights
// ---------------------------------------------------------------------------
__global__ void prep_w(const float* __restrict__ w1, const float* __restrict__ w2,
                       const float* __restrict__ pw2,
                       u16* __restrict__ w1t, u16* __restrict__ w2t, u16* __restrict__ pw2t)
{
    int idx = blockIdx.x * 256 + threadIdx.x;
    if (idx < 16384) {
        { int o = idx >> 6, kk = idx & 63;  w1t[idx] = f2bf(w1[kk * 256 + o]); }
        { int d = idx >> 8, h  = idx & 255; w2t[idx] = f2bf(w2[h * 64 + d]); }
    }
    if (idx < 4096) { int d = idx >> 6, h = idx & 63; pw2t[idx] = f2bf(pw2[h * 64 + d]); }
}

// ---------------------------------------------------------------------------
// prep 2: q = x@theta_w, k = y@phi_w, v = y@g_w   (all (B,N,64) f32 into ws)
// ---------------------------------------------------------------------------
__global__ void prep_qkv(const float* __restrict__ x, const float* __restrict__ y,
                         const float* __restrict__ tw, const float* __restrict__ pw,
                         const float* __restrict__ gw,
                         float* __restrict__ q, float* __restrict__ k, float* __restrict__ v)
{
    __shared__ float xs[4][256];
    __shared__ float ys[4][256];
    const int blk = blockIdx.x;
    const int b = blk >> 6;
    const int n0 = (blk & 63) * 4;
    const int tid = threadIdx.x;
    {
        int r = tid >> 6, e = tid & 63;
        ((float4*)xs[r])[e] = ((const float4*)(x + (size_t)(b * NN + n0 + r) * DIMV))[e];
        ((float4*)ys[r])[e] = ((const float4*)(y + (size_t)(b * NN + n0 + r) * DIMV))[e];
    }
    __syncthreads();
    const int nl = tid >> 6, d = tid & 63;
    float aq = 0.f, ak = 0.f, av = 0.f;
    #pragma unroll 4
    for (int c = 0; c < 256; ++c) {
        float wq = tw[c * 64 + d], wk = pw[c * 64 + d], wv = gw[c * 64 + d];
        float xv = xs[nl][c], yv = ys[nl][c];
        aq += xv * wq; ak += yv * wk; av += yv * wv;
    }
    const int n = n0 + nl;
    q[(b * NN + n) * DI + d] = aq;
    k[(b * NN + n) * DI + d] = ak;
    v[(b * NN + n) * DI + d] = av;
}

// ---------------------------------------------------------------------------
// main fused kernel: one block per (b, i); 4 waves; wave owns rows j0..j0+63.
// Column-interleaved B-fragments: accR/accS col = 4*l15+ct, Hc col = 2*l15+c2.
// sBuf (32 KB): T (fA swizzle) until aT hoist, then Hc chunks (fB swizzle).
// sVB  (32 KB): v_full bf16 packed, fA swizzle. All wave-private regions.
// ---------------------------------------------------------------------------
__global__ __launch_bounds__(256, 2)
void fused_attn(const float* __restrict__ x, const float* __restrict__ x_pos,
                const float* __restrict__ y_pos, const int* __restrict__ mask,
                const float* __restrict__ pw1, const float* __restrict__ pb1,
                const float* __restrict__ pb2,
                const float* __restrict__ ab1, const float* __restrict__ ab2,
                const float* __restrict__ out_w,
                const float* __restrict__ qg, const float* __restrict__ kg,
                const float* __restrict__ vg,
                const u16* __restrict__ w1t, const u16* __restrict__ w2t,
                const u16* __restrict__ pw2t,
                float* __restrict__ out)
{
    __shared__ char sBuf[NN * 128];   // 32 KB: T -> Hc overlay (same object => ordered)
    __shared__ char sVB[NN * 128];    // 32 KB: v_full
    __shared__ float sRed[832];

    const int blk = blockIdx.x;
    const int b = blk >> 8;
    const int i = blk & 255;
    const int tid = threadIdx.x;
    const int l   = tid & 63;
    const int w   = tid >> 6;
    const int j0  = w * 64;
    const int l15 = l & 15;
    const int lh  = l >> 4;

    float* redm = sRed;
    float* reds = sRed + 256;
    float* reda = sRed + 512;
    float* sAgg = sRed + 768;

    // ---- phase 0: pos-MLP layer 1 directly into GEMM0 A-fragments ----
    const float xp0 = x_pos[(b * NN + i) * 3 + 0];
    const float xp1 = x_pos[(b * NN + i) * 3 + 1];
    const float xp2 = x_pos[(b * NN + i) * 3 + 2];

    float w1r[2][4][8];     // [ks][{w0,w1,w2,b1}][cc] for my cols ks*32+lh*8+cc
    #pragma unroll
    for (int ks = 0; ks < 2; ++ks) {
        const int c0 = ks * 32 + lh * 8;
        #pragma unroll
        for (int qq = 0; qq < 2; ++qq) {
            *(f32x4*)&w1r[ks][0][qq*4] = *(const f32x4*)&pw1[0*64 + c0 + qq*4];
            *(f32x4*)&w1r[ks][1][qq*4] = *(const f32x4*)&pw1[1*64 + c0 + qq*4];
            *(f32x4*)&w1r[ks][2][qq*4] = *(const f32x4*)&pw1[2*64 + c0 + qq*4];
            *(f32x4*)&w1r[ks][3][qq*4] = *(const f32x4*)&pb1[c0 + qq*4];
        }
    }
    bf16x8 af[4][2];
    #pragma unroll
    for (int rt = 0; rt < 4; ++rt) {
        const int row = j0 + rt * 16 + l15;
        const float* yp = y_pos + (size_t)(b * NN + row) * 3;
        const float r0 = xp0 - yp[0], r1 = xp1 - yp[1], r2 = xp2 - yp[2];
        #pragma unroll
        for (int ks = 0; ks < 2; ++ks) {
            bf16x8 v;
            #pragma unroll
            for (int cc = 0; cc < 8; ++cc) {
                float h = w1r[ks][3][cc] + r0 * w1r[ks][0][cc] + r1 * w1r[ks][1][cc] + r2 * w1r[ks][2][cc];
                v[cc] = (short)f2bf(fmaxf(h, 0.f));
            }
            af[rt][ks] = v;
        }
    }

    // ---- GEMM0: RPE = hidden @ pos_w2, col-interleaved (col = 4*l15+ct) ----
    f32x4 accR[4][4];
    {
        bf16x8 bfr[4][2];
        #pragma unroll
        for (int ct = 0; ct < 4; ++ct)
            #pragma unroll
            for (int ks = 0; ks < 2; ++ks) {
                const int d = 4 * l15 + ct;
                bfr[ct][ks] = *(const bf16x8*)(pw2t + d * 64 + ks * 32 + lh * 8);
            }
        #pragma unroll
        for (int rt = 0; rt < 4; ++rt)
            #pragma unroll
            for (int ct = 0; ct < 4; ++ct) {
                f32x4 a = {0.f, 0.f, 0.f, 0.f};
                a = __builtin_amdgcn_mfma_f32_16x16x32_bf16(af[rt][0], bfr[ct][0], a, 0, 0, 0);
                a = __builtin_amdgcn_mfma_f32_16x16x32_bf16(af[rt][1], bfr[ct][1], a, 0, 0, 0);
                accR[rt][ct] = a;
            }
    }

    // ---- epilogue: T -> sBuf (b64, fA); v_full -> sVB (b64, fA) ----
    const f32x4 qv   = *(const f32x4*)&qg[((size_t)b * NN + i) * DI + 4 * l15];
    const f32x4 pb2v = *(const f32x4*)&pb2[4 * l15];
    #pragma unroll
    for (int rt = 0; rt < 4; ++rt)
        #pragma unroll
        for (int r = 0; r < 4; ++r) {
            const int row = j0 + rt * 16 + lh * 4 + r;
            const f32x4 kv = *(const f32x4*)&kg[((size_t)b * NN + row) * DI + 4 * l15];
            const f32x4 vv = *(const f32x4*)&vg[((size_t)b * NN + row) * DI + 4 * l15];
            float tv[4], vf[4];
            #pragma unroll
            for (int ct = 0; ct < 4; ++ct) {
                const float rpe = accR[rt][ct][r] + pb2v[ct];
                tv[ct] = qv[ct] - kv[ct] + rpe;
                vf[ct] = vv[ct] + rpe;
            }
            u32x2 tpk; tpk[0] = pack2(tv[0], tv[1]); tpk[1] = pack2(tv[2], tv[3]);
            u32x2 vpk; vpk[0] = pack2(vf[0], vf[1]); vpk[1] = pack2(vf[2], vf[3]);
            const int off = (row * 128 + l15 * 8) ^ fA(row);
            *(u32x2*)(sBuf + off) = tpk;
            *(u32x2*)(sVB  + off) = vpk;
        }

    // ---- hoist GEMM1 A-fragments (T loop-invariant); sBuf then reused as Hc ----
    bf16x8 aT[4][2];
    #pragma unroll
    for (int rt = 0; rt < 4; ++rt) {
        const int rowA = j0 + rt * 16 + l15;
        const int swA = fA(rowA);
        aT[rt][0] = *(const bf16x8*)(sBuf + ((rowA * 128 + lh * 16) ^ swA));
        aT[rt][1] = *(const bf16x8*)(sBuf + ((rowA * 128 + 64 + lh * 16) ^ swA));
    }

    // ---- chunk loop: 8 chunks of 32 hidden; SIM accumulates in regs ----
    f32x4 accS[4][4];
    #pragma unroll
    for (int rt = 0; rt < 4; ++rt)
        #pragma unroll
        for (int ct = 0; ct < 4; ++ct) accS[rt][ct] = (f32x4){0.f, 0.f, 0.f, 0.f};

    for (int hc = 0; hc < 8; ++hc) {
        // pass 1: GEMM1 (Hc col = 2*l15+c2) + relu + packed b32 store
        bf16x8 b1f[2][2];
        #pragma unroll
        for (int c2 = 0; c2 < 2; ++c2)
            #pragma unroll
            for (int ks = 0; ks < 2; ++ks) {
                const int hid = hc * 32 + 2 * l15 + c2;
                b1f[c2][ks] = *(const bf16x8*)(w1t + hid * 64 + ks * 32 + lh * 8);
            }
        bf16x8 b2f[4];
        #pragma unroll
        for (int ct = 0; ct < 4; ++ct) {
            const int d = 4 * l15 + ct;
            b2f[ct] = *(const bf16x8*)(w2t + d * 256 + hc * 32 + lh * 8);
        }
        const f32x2 ab1v = *(const f32x2*)&ab1[hc * 32 + 2 * l15];
        #pragma unroll
        for (int rt = 0; rt < 4; ++rt) {
            f32x4 h0 = {0.f,0.f,0.f,0.f}, h1 = {0.f,0.f,0.f,0.f};
            h0 = __builtin_amdgcn_mfma_f32_16x16x32_bf16(aT[rt][0], b1f[0][0], h0, 0, 0, 0);
            h0 = __builtin_amdgcn_mfma_f32_16x16x32_bf16(aT[rt][1], b1f[0][1], h0, 0, 0, 0);
            h1 = __builtin_amdgcn_mfma_f32_16x16x32_bf16(aT[rt][0], b1f[1][0], h1, 0, 0, 0);
            h1 = __builtin_amdgcn_mfma_f32_16x16x32_bf16(aT[rt][1], b1f[1][1], h1, 0, 0, 0);
            #pragma unroll
            for (int r = 0; r < 4; ++r) {
                const int row = j0 + rt * 16 + lh * 4 + r;
                u32 pk = pack2(fmaxf(h0[r] + ab1v[0], 0.f), fmaxf(h1[r] + ab1v[1], 0.f));
                *(u32*)(sBuf + ((row * 64 + l15 * 4) ^ fB(row))) = pk;
            }
        }
        // pass 2: GEMM2 (SIM col = 4*l15+ct), k = 32 (one MFMA per tile)
        #pragma unroll
        for (int rt = 0; rt < 4; ++rt) {
            const int rowA = j0 + rt * 16 + l15;
            bf16x8 a2 = *(const bf16x8*)(sBuf + ((rowA * 64 + lh * 16) ^ fB(rowA)));
            #pragma unroll
            for (int ct = 0; ct < 4; ++ct)
                accS[rt][ct] = __builtin_amdgcn_mfma_f32_16x16x32_bf16(a2, b2f[ct], accS[rt][ct], 0, 0, 0);
        }
    }

    // ---- softmax: fully in-register over accS; cross-lane + cross-wave ----
    const f32x4 ab2v = *(const f32x4*)&ab2[4 * l15];
    const int mjl = mask[b * NN + j0 + l];
    const unsigned long long mb = __ballot(mjl != 0);
    const bool mi_b = mask[b * NN + i] != 0;

    float mx[4] = {-NEGMAX, -NEGMAX, -NEGMAX, -NEGMAX};
    #pragma unroll
    for (int rt = 0; rt < 4; ++rt)
        #pragma unroll
        for (int r = 0; r < 4; ++r) {
            const int ro = rt * 16 + lh * 4 + r;
            const bool bit = mi_b && ((mb >> ro) & 1ull);
            #pragma unroll
            for (int ct = 0; ct < 4; ++ct) {
                float s = bit ? (accS[rt][ct][r] + ab2v[ct]) : -NEGMAX;
                accS[rt][ct][r] = s;
                mx[ct] = fmaxf(mx[ct], s);
            }
        }
    #pragma unroll
    for (int ct = 0; ct < 4; ++ct) {
        mx[ct] = fmaxf(mx[ct], __shfl_xor(mx[ct], 16));
        mx[ct] = fmaxf(mx[ct], __shfl_xor(mx[ct], 32));
    }
    if (lh == 0)
        *(f32x4*)&redm[w * 64 + 4 * l15] = (f32x4){mx[0], mx[1], mx[2], mx[3]};
    __syncthreads();
    float m4[4];
    {
        f32x4 a0 = *(f32x4*)&redm[      4 * l15];
        f32x4 a1 = *(f32x4*)&redm[ 64 + 4 * l15];
        f32x4 a2 = *(f32x4*)&redm[128 + 4 * l15];
        f32x4 a3 = *(f32x4*)&redm[192 + 4 * l15];
        #pragma unroll
        for (int ct = 0; ct < 4; ++ct)
            m4[ct] = fmaxf(fmaxf(a0[ct], a1[ct]), fmaxf(a2[ct], a3[ct]));
    }
    float ssum[4] = {0.f, 0.f, 0.f, 0.f}, sagg[4] = {0.f, 0.f, 0.f, 0.f};
    #pragma unroll
    for (int rt = 0; rt < 4; ++rt)
        #pragma unroll
        for (int r = 0; r < 4; ++r) {
            const int row = j0 + rt * 16 + lh * 4 + r;
            const u32x2 vpk = *(const u32x2*)(sVB + ((row * 128 + l15 * 8) ^ fA(row)));
            const float vfs[4] = {ubf_lo(vpk[0]), ubf_hi(vpk[0]), ubf_lo(vpk[1]), ubf_hi(vpk[1])};
            #pragma unroll
            for (int ct = 0; ct < 4; ++ct) {
                const float e = __expf(accS[rt][ct][r] - m4[ct]);
                ssum[ct] += e;
                sagg[ct] += e * vfs[ct];
            }
        }
    #pragma unroll
    for (int ct = 0; ct < 4; ++ct) {
        ssum[ct] += __shfl_xor(ssum[ct], 16);
        ssum[ct] += __shfl_xor(ssum[ct], 32);
        sagg[ct] += __shfl_xor(sagg[ct], 16);
        sagg[ct] += __shfl_xor(sagg[ct], 32);
    }
    if (lh == 0) {
        *(f32x4*)&reds[w * 64 + 4 * l15] = (f32x4){ssum[0], ssum[1], ssum[2], ssum[3]};
        *(f32x4*)&reda[w * 64 + 4 * l15] = (f32x4){sagg[0], sagg[1], sagg[2], sagg[3]};
    }
    __syncthreads();
    if (tid < 64) {
        float den = reds[tid] + reds[64 + tid] + reds[128 + tid] + reds[192 + tid];
        float ag  = reda[tid] + reda[64 + tid] + reda[128 + tid] + reda[192 + tid];
        sAgg[tid] = ag / den;
    }
    __syncthreads();

    // ---- phase 4: out[i,:] = x[i,:] + agg @ out_w ----
    {
        float acc = 0.f;
        #pragma unroll 8
        for (int d = 0; d < 64; ++d)
            acc += sAgg[d] * out_w[d * DIMV + tid];
        const int o = (b * NN + i) * DIMV + tid;
        out[o] = x[o] + acc;
    }
}

// ---------------------------------------------------------------------------
extern "C" void kernel_launch(void* const* d_in, const int* in_sizes, int n_in,
                              void* d_out, int out_size, void* d_ws, size_t ws_size,
                              hipStream_t stream)
{
    const float* x       = (const float*)d_in[0];
    const float* y       = (const float*)d_in[1];
    const float* x_pos   = (const float*)d_in[2];
    const float* y_pos   = (const float*)d_in[3];
    const int*   mask    = (const int*)d_in[4];
    const float* g_w     = (const float*)d_in[5];
    const float* theta_w = (const float*)d_in[6];
    const float* phi_w   = (const float*)d_in[7];
    const float* pos_w1  = (const float*)d_in[8];
    const float* pos_b1  = (const float*)d_in[9];
    const float* pos_w2  = (const float*)d_in[10];
    const float* pos_b2  = (const float*)d_in[11];
    const float* attn_w1 = (const float*)d_in[12];
    const float* attn_b1 = (const float*)d_in[13];
    const float* attn_w2 = (const float*)d_in[14];
    const float* attn_b2 = (const float*)d_in[15];
    const float* out_w   = (const float*)d_in[16];

    float* q = (float*)d_ws;
    float* k = q + NB * NN * DI;
    float* v = k + NB * NN * DI;
    u16* w1t  = (u16*)(v + NB * NN * DI);   // 256*64
    u16* w2t  = w1t + 256 * 64;             // 64*256
    u16* pw2t = w2t + 64 * 256;             // 64*64

    prep_w<<<64, 256, 0, stream>>>(attn_w1, attn_w2, pos_w2, w1t, w2t, pw2t);
    prep_qkv<<<512, 256, 0, stream>>>(x, y, theta_w, phi_w, g_w, q, k, v);
    fused_attn<<<NB * NN, 256, 0, stream>>>(x, x_pos, y_pos, mask,
                                            pos_w1, pos_b1, pos_b2,
                                            attn_b1, attn_b2, out_w,
                                            q, k, v, w1t, w2t, pw2t,
                                            (float*)d_out);
}

// Round 4
// 117.648 us; speedup vs baseline: 1.4528x; 1.0105x over previous
//
#include <hip/hip_runtime.h>
#include <hip/hip_bf16.h>

#define NB 8
#define NN 256
#define DIMV 256
#define DI 64
#define NEGMAX 3.402823466e+38f

typedef unsigned short u16;
typedef unsigned int u32;
typedef __attribute__((ext_vector_type(8))) short bf16x8;
typedef __attribute__((ext_vector_type(4))) float f32x4;
typedef __attribute__((ext_vector_type(2))) float f32x2;
typedef __attribute__((ext_vector_type(2))) unsigned int u32x2;

__device__ __forceinline__ u16 f2bf(float f) {
    __hip_bfloat16 h = __float2bfloat16(f);
    u16 u; __builtin_memcpy(&u, &h, 2); return u;
}
__device__ __forceinline__ u32 pack2(float a, float b) {
    return (u32)f2bf(a) | ((u32)f2bf(b) << 16);
}
__device__ __forceinline__ float ubf_lo(u32 u) {
    union { u32 u; float f; } x; x.u = u << 16; return x.f;
}
__device__ __forceinline__ float ubf_hi(u32 u) {
    union { u32 u; float f; } x; x.u = u & 0xffff0000u; return x.f;
}
// swizzles: fA for 128B-stride rows, fB for 64B-stride rows (bits 4-6 only)
__device__ __forceinline__ int fA(int row) { return ((row & 7) << 4) ^ ((row & 8) << 2); }
__device__ __forceinline__ int fB(int row) { return ((row >> 1) & 7) << 4; }

// ---------------------------------------------------------------------------
// prep 1: transpose + bf16-convert GEMM B-operand weights
// ---------------------------------------------------------------------------
__global__ void prep_w(const float* __restrict__ w1, const float* __restrict__ w2,
                       const float* __restrict__ pw2,
                       u16* __restrict__ w1t, u16* __restrict__ w2t, u16* __restrict__ pw2t)
{
    int idx = blockIdx.x * 256 + threadIdx.x;
    if (idx < 16384) {
        { int o = idx >> 6, kk = idx & 63;  w1t[idx] = f2bf(w1[kk * 256 + o]); }
        { int d = idx >> 8, h  = idx & 255; w2t[idx] = f2bf(w2[h * 64 + d]); }
    }
    if (idx < 4096) { int d = idx >> 6, h = idx & 63; pw2t[idx] = f2bf(pw2[h * 64 + d]); }
}

// ---------------------------------------------------------------------------
// prep 2: q = x@theta_w, k = y@phi_w, v = y@g_w   (all (B,N,64) f32 into ws)
// ---------------------------------------------------------------------------
__global__ void prep_qkv(const float* __restrict__ x, const float* __restrict__ y,
                         const float* __restrict__ tw, const float* __restrict__ pw,
                         const float* __restrict__ gw,
                         float* __restrict__ q, float* __restrict__ k, float* __restrict__ v)
{
    __shared__ float xs[4][256];
    __shared__ float ys[4][256];
    const int blk = blockIdx.x;
    const int b = blk >> 6;
    const int n0 = (blk & 63) * 4;
    const int tid = threadIdx.x;
    {
        int r = tid >> 6, e = tid & 63;
        ((float4*)xs[r])[e] = ((const float4*)(x + (size_t)(b * NN + n0 + r) * DIMV))[e];
        ((float4*)ys[r])[e] = ((const float4*)(y + (size_t)(b * NN + n0 + r) * DIMV))[e];
    }
    __syncthreads();
    const int nl = tid >> 6, d = tid & 63;
    float aq = 0.f, ak = 0.f, av = 0.f;
    #pragma unroll 4
    for (int c = 0; c < 256; ++c) {
        float wq = tw[c * 64 + d], wk = pw[c * 64 + d], wv = gw[c * 64 + d];
        float xv = xs[nl][c], yv = ys[nl][c];
        aq += xv * wq; ak += yv * wk; av += yv * wv;
    }
    const int n = n0 + nl;
    q[(b * NN + n) * DI + d] = aq;
    k[(b * NN + n) * DI + d] = ak;
    v[(b * NN + n) * DI + d] = av;
}

// ---------------------------------------------------------------------------
// main fused kernel: one block per (b, i); 4 waves; wave owns rows j0..j0+63.
// LDS: sHcS 16 KB (per-wave 4 KB: T-stage 2 KB overlay -> Hc chunks),
//      sVB 32 KB (v_full bf16, fA swizzle), sRed 3.3 KB.  Total 51.3 KB
//      -> 3 blocks/CU.
// Column-interleaved B-fragments: accR/accS col = 4*l15+ct, Hc col = 2*l15+c2.
// ---------------------------------------------------------------------------
__global__ __launch_bounds__(256, 2)
void fused_attn(const float* __restrict__ x, const float* __restrict__ x_pos,
                const float* __restrict__ y_pos, const int* __restrict__ mask,
                const float* __restrict__ pw1, const float* __restrict__ pb1,
                const float* __restrict__ pb2,
                const float* __restrict__ ab1, const float* __restrict__ ab2,
                const float* __restrict__ out_w,
                const float* __restrict__ qg, const float* __restrict__ kg,
                const float* __restrict__ vg,
                const u16* __restrict__ w1t, const u16* __restrict__ w2t,
                const u16* __restrict__ pw2t,
                float* __restrict__ out)
{
    __shared__ char sHcS[4][4096];    // 16 KB: per-wave stage(2KB) -> Hc(4KB)
    __shared__ char sVB[NN * 128];    // 32 KB: v_full
    __shared__ float sRed[832];

    const int blk = blockIdx.x;
    const int b = blk >> 8;
    const int i = blk & 255;
    const int tid = threadIdx.x;
    const int l   = tid & 63;
    const int w   = tid >> 6;
    const int j0  = w * 64;
    const int l15 = l & 15;
    const int lh  = l >> 4;

    char* const stg = sHcS[w];
    float* redm = sRed;
    float* reds = sRed + 256;
    float* reda = sRed + 512;
    float* sAgg = sRed + 768;

    // hoisted LDS address bases (all rt-invariant; rt enters as imm offset)
    int stW[4], vA[4];
    #pragma unroll
    for (int r = 0; r < 4; ++r) {
        const int lrs = lh * 4 + r;
        stW[r] = (lrs * 128 + l15 * 8) ^ fA(lrs);
        const int rowl = j0 + lrs;                 // + rt*16 via imm
        vA[r] = (rowl * 128 + l15 * 8) ^ fA(rowl); // fA depends on row&15 only
    }
    const int stR0 = (l15 * 128 + lh * 16) ^ fA(l15);
    const int stR1 = stR0 ^ 64;
    int hcW[4], hcR;
    #pragma unroll
    for (int r = 0; r < 4; ++r) {
        const int lr = lh * 4 + r;                 // + rt*16 via imm (fB rt-invariant)
        hcW[r] = (lr * 64 + l15 * 4) ^ fB(lr);
    }
    hcR = (l15 * 64 + lh * 16) ^ fB(l15);

    // ---- mask (early, hide latency) ----
    const int mjl = mask[b * NN + j0 + l];
    const unsigned long long mb = __ballot(mjl != 0);
    const bool mi_b = mask[b * NN + i] != 0;

    // ---- phase 0: pos-MLP layer 1 directly into GEMM0 A-fragments ----
    const float xp0 = x_pos[(b * NN + i) * 3 + 0];
    const float xp1 = x_pos[(b * NN + i) * 3 + 1];
    const float xp2 = x_pos[(b * NN + i) * 3 + 2];

    float w1r[2][4][8];     // [ks][{w0,w1,w2,b1}][cc] for cols ks*32+lh*8+cc
    #pragma unroll
    for (int ks = 0; ks < 2; ++ks) {
        const int c0 = ks * 32 + lh * 8;
        #pragma unroll
        for (int qq = 0; qq < 2; ++qq) {
            *(f32x4*)&w1r[ks][0][qq*4] = *(const f32x4*)&pw1[0*64 + c0 + qq*4];
            *(f32x4*)&w1r[ks][1][qq*4] = *(const f32x4*)&pw1[1*64 + c0 + qq*4];
            *(f32x4*)&w1r[ks][2][qq*4] = *(const f32x4*)&pw1[2*64 + c0 + qq*4];
            *(f32x4*)&w1r[ks][3][qq*4] = *(const f32x4*)&pb1[c0 + qq*4];
        }
    }
    bf16x8 af[4][2];
    #pragma unroll
    for (int rt = 0; rt < 4; ++rt) {
        const int row = j0 + rt * 16 + l15;
        const float* yp = y_pos + (size_t)(b * NN + row) * 3;
        const float r0 = xp0 - yp[0], r1 = xp1 - yp[1], r2 = xp2 - yp[2];
        #pragma unroll
        for (int ks = 0; ks < 2; ++ks) {
            bf16x8 v;
            #pragma unroll
            for (int cc = 0; cc < 8; ++cc) {
                float h = w1r[ks][3][cc] + r0 * w1r[ks][0][cc] + r1 * w1r[ks][1][cc] + r2 * w1r[ks][2][cc];
                v[cc] = (short)f2bf(fmaxf(h, 0.f));
            }
            af[rt][ks] = v;
        }
    }

    // ---- GEMM0 + epilogue, rt-by-rt through the 2 KB stage; build aT ----
    const f32x4 qv   = *(const f32x4*)&qg[((size_t)b * NN + i) * DI + 4 * l15];
    const f32x4 pb2v = *(const f32x4*)&pb2[4 * l15];
    bf16x8 bfr[4][2];
    #pragma unroll
    for (int ct = 0; ct < 4; ++ct)
        #pragma unroll
        for (int ks = 0; ks < 2; ++ks) {
            const int d = 4 * l15 + ct;
            bfr[ct][ks] = *(const bf16x8*)(pw2t + d * 64 + ks * 32 + lh * 8);
        }
    bf16x8 aT[4][2];
    #pragma unroll
    for (int rt = 0; rt < 4; ++rt) {
        f32x4 accR[4];
        #pragma unroll
        for (int ct = 0; ct < 4; ++ct) {
            f32x4 a = {pb2v[ct], pb2v[ct], pb2v[ct], pb2v[ct]};   // pb2 folded in
            a = __builtin_amdgcn_mfma_f32_16x16x32_bf16(af[rt][0], bfr[ct][0], a, 0, 0, 0);
            a = __builtin_amdgcn_mfma_f32_16x16x32_bf16(af[rt][1], bfr[ct][1], a, 0, 0, 0);
            accR[ct] = a;
        }
        #pragma unroll
        for (int r = 0; r < 4; ++r) {
            const int row = j0 + rt * 16 + lh * 4 + r;
            const f32x4 kv = *(const f32x4*)&kg[((size_t)b * NN + row) * DI + 4 * l15];
            const f32x4 vv = *(const f32x4*)&vg[((size_t)b * NN + row) * DI + 4 * l15];
            float tv[4], vf[4];
            #pragma unroll
            for (int ct = 0; ct < 4; ++ct) {
                const float rpe = accR[ct][r];
                tv[ct] = qv[ct] - kv[ct] + rpe;
                vf[ct] = vv[ct] + rpe;
            }
            u32x2 tpk; tpk[0] = pack2(tv[0], tv[1]); tpk[1] = pack2(tv[2], tv[3]);
            u32x2 vpk; vpk[0] = pack2(vf[0], vf[1]); vpk[1] = pack2(vf[2], vf[3]);
            *(u32x2*)(stg + stW[r]) = tpk;
            *(u32x2*)(sVB + vA[r] + rt * 2048) = vpk;
        }
        aT[rt][0] = *(const bf16x8*)(stg + stR0);
        aT[rt][1] = *(const bf16x8*)(stg + stR1);
    }

    // ---- chunk loop: 8 chunks of 32 hidden; SIM accumulates in regs ----
    const f32x4 ab2v = *(const f32x4*)&ab2[4 * l15];
    f32x4 accS[4][4];
    #pragma unroll
    for (int rt = 0; rt < 4; ++rt)
        #pragma unroll
        for (int ct = 0; ct < 4; ++ct)
            accS[rt][ct] = (f32x4){ab2v[ct], ab2v[ct], ab2v[ct], ab2v[ct]};  // ab2 folded

    for (int hc = 0; hc < 8; ++hc) {
        bf16x8 b1f[2][2];
        #pragma unroll
        for (int c2 = 0; c2 < 2; ++c2)
            #pragma unroll
            for (int ks = 0; ks < 2; ++ks) {
                const int hid = hc * 32 + 2 * l15 + c2;
                b1f[c2][ks] = *(const bf16x8*)(w1t + hid * 64 + ks * 32 + lh * 8);
            }
        bf16x8 b2f[4];
        #pragma unroll
        for (int ct = 0; ct < 4; ++ct) {
            const int d = 4 * l15 + ct;
            b2f[ct] = *(const bf16x8*)(w2t + d * 256 + hc * 32 + lh * 8);
        }
        const f32x2 ab1v = *(const f32x2*)&ab1[hc * 32 + 2 * l15];
        const f32x4 ib0 = {ab1v[0], ab1v[0], ab1v[0], ab1v[0]};
        const f32x4 ib1 = {ab1v[1], ab1v[1], ab1v[1], ab1v[1]};
        #pragma unroll
        for (int rt = 0; rt < 4; ++rt) {
            f32x4 h0 = ib0, h1 = ib1;                     // ab1 folded in
            h0 = __builtin_amdgcn_mfma_f32_16x16x32_bf16(aT[rt][0], b1f[0][0], h0, 0, 0, 0);
            h0 = __builtin_amdgcn_mfma_f32_16x16x32_bf16(aT[rt][1], b1f[0][1], h0, 0, 0, 0);
            h1 = __builtin_amdgcn_mfma_f32_16x16x32_bf16(aT[rt][0], b1f[1][0], h1, 0, 0, 0);
            h1 = __builtin_amdgcn_mfma_f32_16x16x32_bf16(aT[rt][1], b1f[1][1], h1, 0, 0, 0);
            #pragma unroll
            for (int r = 0; r < 4; ++r)
                *(u32*)(stg + hcW[r] + rt * 1024) =
                    pack2(fmaxf(h0[r], 0.f), fmaxf(h1[r], 0.f));
        }
        #pragma unroll
        for (int rt = 0; rt < 4; ++rt) {
            bf16x8 a2 = *(const bf16x8*)(stg + hcR + rt * 1024);
            #pragma unroll
            for (int ct = 0; ct < 4; ++ct)
                accS[rt][ct] = __builtin_amdgcn_mfma_f32_16x16x32_bf16(a2, b2f[ct], accS[rt][ct], 0, 0, 0);
        }
    }

    // ---- softmax: fully in-register over accS; cross-lane + cross-wave ----
    float mx[4] = {-NEGMAX, -NEGMAX, -NEGMAX, -NEGMAX};
    #pragma unroll
    for (int rt = 0; rt < 4; ++rt)
        #pragma unroll
        for (int r = 0; r < 4; ++r) {
            const int ro = rt * 16 + lh * 4 + r;
            const bool bit = mi_b && ((mb >> ro) & 1ull);
            #pragma unroll
            for (int ct = 0; ct < 4; ++ct) {
                float s = bit ? accS[rt][ct][r] : -NEGMAX;
                accS[rt][ct][r] = s;
                mx[ct] = fmaxf(mx[ct], s);
            }
        }
    #pragma unroll
    for (int ct = 0; ct < 4; ++ct) {
        mx[ct] = fmaxf(mx[ct], __shfl_xor(mx[ct], 16));
        mx[ct] = fmaxf(mx[ct], __shfl_xor(mx[ct], 32));
    }
    if (lh == 0)
        *(f32x4*)&redm[w * 64 + 4 * l15] = (f32x4){mx[0], mx[1], mx[2], mx[3]};
    __syncthreads();
    float m4[4];
    {
        f32x4 a0 = *(f32x4*)&redm[      4 * l15];
        f32x4 a1 = *(f32x4*)&redm[ 64 + 4 * l15];
        f32x4 a2 = *(f32x4*)&redm[128 + 4 * l15];
        f32x4 a3 = *(f32x4*)&redm[192 + 4 * l15];
        #pragma unroll
        for (int ct = 0; ct < 4; ++ct)
            m4[ct] = fmaxf(fmaxf(a0[ct], a1[ct]), fmaxf(a2[ct], a3[ct]));
    }
    float ssum[4] = {0.f, 0.f, 0.f, 0.f}, sagg[4] = {0.f, 0.f, 0.f, 0.f};
    #pragma unroll
    for (int rt = 0; rt < 4; ++rt)
        #pragma unroll
        for (int r = 0; r < 4; ++r) {
            const u32x2 vpk = *(const u32x2*)(sVB + vA[r] + rt * 2048);
            const float vfs[4] = {ubf_lo(vpk[0]), ubf_hi(vpk[0]), ubf_lo(vpk[1]), ubf_hi(vpk[1])};
            #pragma unroll
            for (int ct = 0; ct < 4; ++ct) {
                const float e = __expf(accS[rt][ct][r] - m4[ct]);
                ssum[ct] += e;
                sagg[ct] += e * vfs[ct];
            }
        }
    #pragma unroll
    for (int ct = 0; ct < 4; ++ct) {
        ssum[ct] += __shfl_xor(ssum[ct], 16);
        ssum[ct] += __shfl_xor(ssum[ct], 32);
        sagg[ct] += __shfl_xor(sagg[ct], 16);
        sagg[ct] += __shfl_xor(sagg[ct], 32);
    }
    if (lh == 0) {
        *(f32x4*)&reds[w * 64 + 4 * l15] = (f32x4){ssum[0], ssum[1], ssum[2], ssum[3]};
        *(f32x4*)&reda[w * 64 + 4 * l15] = (f32x4){sagg[0], sagg[1], sagg[2], sagg[3]};
    }
    __syncthreads();
    if (tid < 64) {
        float den = reds[tid] + reds[64 + tid] + reds[128 + tid] + reds[192 + tid];
        float ag  = reda[tid] + reda[64 + tid] + reda[128 + tid] + reda[192 + tid];
        sAgg[tid] = ag / den;
    }
    __syncthreads();

    // ---- phase 4: out[i,:] = x[i,:] + agg @ out_w ----
    {
        float acc = 0.f;
        #pragma unroll 8
        for (int d = 0; d < 64; ++d)
            acc += sAgg[d] * out_w[d * DIMV + tid];
        const int o = (b * NN + i) * DIMV + tid;
        out[o] = x[o] + acc;
    }
}

// ---------------------------------------------------------------------------
extern "C" void kernel_launch(void* const* d_in, const int* in_sizes, int n_in,
                              void* d_out, int out_size, void* d_ws, size_t ws_size,
                              hipStream_t stream)
{
    const float* x       = (const float*)d_in[0];
    const float* y       = (const float*)d_in[1];
    const float* x_pos   = (const float*)d_in[2];
    const float* y_pos   = (const float*)d_in[3];
    const int*   mask    = (const int*)d_in[4];
    const float* g_w     = (const float*)d_in[5];
    const float* theta_w = (const float*)d_in[6];
    const float* phi_w   = (const float*)d_in[7];
    const float* pos_w1  = (const float*)d_in[8];
    const float* pos_b1  = (const float*)d_in[9];
    const float* pos_w2  = (const float*)d_in[10];
    const float* pos_b2  = (const float*)d_in[11];
    const float* attn_w1 = (const float*)d_in[12];
    const float* attn_b1 = (const float*)d_in[13];
    const float* attn_w2 = (const float*)d_in[14];
    const float* attn_b2 = (const float*)d_in[15];
    const float* out_w   = (const float*)d_in[16];

    float* q = (float*)d_ws;
    float* k = q + NB * NN * DI;
    float* v = k + NB * NN * DI;
    u16* w1t  = (u16*)(v + NB * NN * DI);   // 256*64
    u16* w2t  = w1t + 256 * 64;             // 64*256
    u16* pw2t = w2t + 64 * 256;             // 64*64

    prep_w<<<64, 256, 0, stream>>>(attn_w1, attn_w2, pos_w2, w1t, w2t, pw2t);
    prep_qkv<<<512, 256, 0, stream>>>(x, y, theta_w, phi_w, g_w, q, k, v);
    fused_attn<<<NB * NN, 256, 0, stream>>>(x, x_pos, y_pos, mask,
                                            pos_w1, pos_b1, pos_b2,
                                            attn_b1, attn_b2, out_w,
                                            q, k, v, w1t, w2t, pw2t,
                                            (float*)d_out);
}